// Round 2
// baseline (255.397 us; speedup 1.0000x reference)
//
#include <hip/hip_runtime.h>
#include <hip/hip_bf16.h>

#define MASK_ID 3
#define MAX_SEN 128
#define NB 8
#define SEQ 8192
#define EMB 1024
#define DIM 128
#define TS 32

typedef __attribute__((ext_vector_type(8))) short short8v;   // 8 bf16 (4 VGPRs)
typedef __attribute__((ext_vector_type(4))) float f32x4;     // MFMA accumulator

#define MFMA(a, b, c) __builtin_amdgcn_mfma_f32_16x16x32_bf16(a, b, c, 0, 0, 0)

// fp32 -> bf16 (round-nearest-even), returned as raw short
__device__ __forceinline__ short f2b(float x) {
    union { float f; unsigned u; } v; v.f = x;
    unsigned r = (v.u + 0x7FFFu + ((v.u >> 16) & 1u)) >> 16;
    return (short)r;
}

// ---------------- Kernel 1: per-row scan -> mask positions + nvis ----------------
__global__ __launch_bounds__(1024) void seg_kernel(const int* __restrict__ ids,
                                                   int* __restrict__ pos,
                                                   int* __restrict__ nvis) {
    int b = blockIdx.x;
    int tid = threadIdx.x;
    __shared__ int sc[1024];
    __shared__ int sc2[1024];
    const int PER = SEQ / 1024;  // 8
    int base = b * SEQ + tid * PER;

    int ids_l[PER];
    int cnt = 0;
    #pragma unroll
    for (int j = 0; j < PER; j++) {
        ids_l[j] = ids[base + j];
        cnt += (ids_l[j] == MASK_ID) ? 1 : 0;
    }
    if (tid < MAX_SEN) pos[b * MAX_SEN + tid] = -1;
    sc[tid] = cnt;
    __syncthreads();

    int* src = sc;
    int* dst = sc2;
    for (int off = 1; off < 1024; off <<= 1) {
        int v = src[tid];
        if (tid >= off) v += src[tid - off];
        dst[tid] = v;
        __syncthreads();
        int* t = src; src = dst; dst = t;
    }
    int incl = src[tid];
    int run = incl - cnt;  // exclusive prefix

    #pragma unroll
    for (int j = 0; j < PER; j++) {
        if (ids_l[j] == MASK_ID) {
            run++;
            if (run <= MAX_SEN) pos[b * MAX_SEN + run - 1] = tid * PER + j;
        }
        int nv = run; if (nv > MAX_SEN) nv = MAX_SEN;
        nvis[base + j] = nv;
    }
}

// ---------------- Kernel 2: transpose+convert weights to bf16 ----------------
// WqT[d][e] = bf16(Wq[e][d]);  WoT[e][d] = bf16(Wo[d][e])
__global__ __launch_bounds__(256) void prep_w(const float* __restrict__ Wq,
                                              const float* __restrict__ Wo,
                                              short* __restrict__ WqT,
                                              short* __restrict__ WoT) {
    int idx = blockIdx.x * 256 + threadIdx.x;      // 0 .. 131071
    int d = idx >> 10, e = idx & 1023;
    WqT[idx] = f2b(Wq[e * DIM + d]);
    int e2 = idx >> 7, d2 = idx & 127;
    WoT[idx] = f2b(Wo[d2 * EMB + e2]);
}

// ---------------- Kernel 3: static_sen = gather(hidden)@Wv + bv (fp32) ----------------
__global__ __launch_bounds__(128) void static_kernel(const float* __restrict__ hidden,
                                                     const float* __restrict__ Wv,
                                                     const float* __restrict__ bv,
                                                     const int* __restrict__ pos,
                                                     float* __restrict__ stat) {
    int m = blockIdx.x, b = blockIdx.y;
    int d = threadIdx.x;
    __shared__ float h[EMB];
    int p = pos[b * MAX_SEN + m];   // uniform across block
    float acc = bv[d];
    if (p >= 0) {
        const float* hp = hidden + ((size_t)b * SEQ + p) * EMB;
        for (int e = d; e < EMB; e += 128) h[e] = hp[e];
        __syncthreads();
        for (int e = 0; e < EMB; e++) acc += h[e] * Wv[e * DIM + d];
    }
    stat[(b * MAX_SEN + m) * DIM + d] = acc;
}

// ---------------- Kernel 4: k_bf[m][d] and vT_bf[d][m] (bf16) ----------------
__global__ __launch_bounds__(128) void kv_kernel(const float* __restrict__ stat,
                                                 const float* __restrict__ Wk, const float* __restrict__ bk,
                                                 const float* __restrict__ Wvt, const float* __restrict__ bvt,
                                                 short* __restrict__ k_bf, short* __restrict__ vT_bf) {
    int m = blockIdx.x, b = blockIdx.y;
    int d = threadIdx.x;
    __shared__ float srow[DIM];
    srow[d] = stat[(b * MAX_SEN + m) * DIM + d];
    __syncthreads();
    float ka = bk[d], va = bvt[d];
    for (int e = 0; e < DIM; e++) {
        float sv = srow[e];
        ka += sv * Wk[e * DIM + d];
        va += sv * Wvt[e * DIM + d];
    }
    k_bf[((size_t)b * MAX_SEN + m) * DIM + d] = f2b(ka);
    vT_bf[((size_t)b * DIM + d) * MAX_SEN + m] = f2b(va);
}

// ---------------- Kernel 5: fused MFMA attention per 32-token tile ----------------
__global__ __launch_bounds__(256, 2) void attn_kernel(
    const float* __restrict__ hidden,
    const short* __restrict__ WqT, const float* __restrict__ bq,
    const short* __restrict__ k_bf, const short* __restrict__ vT_bf,
    const short* __restrict__ WoT, const float* __restrict__ bo,
    const int* __restrict__ nvis,
    float* __restrict__ out) {
    int blk = blockIdx.x;
    int b  = blk >> 8;             // 256 tiles per batch
    int s0 = (blk & 255) * TS;
    int tid = threadIdx.x;
    int lane = tid & 63;
    int w  = tid >> 6;             // wave 0..3
    int lr = lane & 15;
    int lq = lane >> 4;            // quarter 0..3

    __shared__ short hA[32 * 256];    // hidden chunk, bf16, swizzled rows of 512B
    __shared__ short qP[32 * 128];    // q then P, bf16, swizzled rows of 256B
    __shared__ short odB[32 * 128];   // attn output (d-space), bf16, swizzled
    __shared__ float lg[32 * 132];    // logits fp32

    char* hAc = (char*)hA;
    char* qPc = (char*)qP;
    char* odc = (char*)odB;

    const size_t hrow = (size_t)b * SEQ + s0;
    f32x4 zero = {0.f, 0.f, 0.f, 0.f};

    // ================= phase 1: q = (H @ Wq + bq) * scale =================
    f32x4 a00 = zero, a01 = zero, a10 = zero, a11 = zero;
    for (int ec = 0; ec < 4; ec++) {
        __syncthreads();
        #pragma unroll
        for (int g = 0; g < 4; g++) {
            int G = tid + g * 256;
            int t = G >> 5;
            int e8 = (G & 31) << 3;
            const float* hp = hidden + (hrow + t) * EMB + ec * 256 + e8;
            float4 f0 = *(const float4*)hp;
            float4 f1 = *(const float4*)(hp + 4);
            short8v hh;
            hh[0] = f2b(f0.x); hh[1] = f2b(f0.y); hh[2] = f2b(f0.z); hh[3] = f2b(f0.w);
            hh[4] = f2b(f1.x); hh[5] = f2b(f1.y); hh[6] = f2b(f1.z); hh[7] = f2b(f1.w);
            int byte = (t * 512 + e8 * 2) ^ ((t & 7) << 4);
            *(short8v*)(hAc + byte) = hh;
        }
        __syncthreads();
        const short* bp0 = WqT + (w * 32 + lr) * 1024 + ec * 256 + lq * 8;
        const short* bp1 = bp0 + 16 * 1024;
        #pragma unroll
        for (int kk = 0; kk < 8; kk++) {
            short8v fa0 = *(short8v*)(hAc + ((lr * 512 + kk * 64 + lq * 16) ^ ((lr & 7) << 4)));
            short8v fa1 = *(short8v*)(hAc + (((16 + lr) * 512 + kk * 64 + lq * 16) ^ ((lr & 7) << 4)));
            short8v fb0 = *(const short8v*)(bp0 + kk * 32);
            short8v fb1 = *(const short8v*)(bp1 + kk * 32);
            a00 = MFMA(fa0, fb0, a00); a01 = MFMA(fa0, fb1, a01);
            a10 = MFMA(fa1, fb0, a10); a11 = MFMA(fa1, fb1, a11);
        }
    }
    {
        const float scale = 0.08838834764831845f;  // 128^-0.5
        int d0 = w * 32 + lr;
        float bq0 = bq[d0], bq1 = bq[d0 + 16];
        #pragma unroll
        for (int r = 0; r < 4; r++) {
            int r0 = lq * 4 + r, r1 = 16 + r0;
            *(short*)(qPc + ((r0 * 256 + d0 * 2) ^ ((r0 & 7) << 4)))        = f2b((a00[r] + bq0) * scale);
            *(short*)(qPc + ((r0 * 256 + (d0 + 16) * 2) ^ ((r0 & 7) << 4))) = f2b((a01[r] + bq1) * scale);
            *(short*)(qPc + ((r1 * 256 + d0 * 2) ^ ((r1 & 7) << 4)))        = f2b((a10[r] + bq0) * scale);
            *(short*)(qPc + ((r1 * 256 + (d0 + 16) * 2) ^ ((r1 & 7) << 4))) = f2b((a11[r] + bq1) * scale);
        }
    }
    __syncthreads();

    // ================= phase 2: logits = q @ K^T =================
    {
        f32x4 l00 = zero, l01 = zero, l10 = zero, l11 = zero;
        const short* kbp0 = k_bf + ((size_t)b << 14) + (w * 32 + lr) * 128 + lq * 8;
        const short* kbp1 = kbp0 + 16 * 128;
        #pragma unroll
        for (int kk = 0; kk < 4; kk++) {
            short8v fa0 = *(short8v*)(qPc + ((lr * 256 + kk * 64 + lq * 16) ^ ((lr & 7) << 4)));
            short8v fa1 = *(short8v*)(qPc + (((16 + lr) * 256 + kk * 64 + lq * 16) ^ ((lr & 7) << 4)));
            short8v fb0 = *(const short8v*)(kbp0 + kk * 32);
            short8v fb1 = *(const short8v*)(kbp1 + kk * 32);
            l00 = MFMA(fa0, fb0, l00); l01 = MFMA(fa0, fb1, l01);
            l10 = MFMA(fa1, fb0, l10); l11 = MFMA(fa1, fb1, l11);
        }
        int m0 = w * 32 + lr;
        #pragma unroll
        for (int r = 0; r < 4; r++) {
            int r0 = lq * 4 + r, r1 = 16 + r0;
            lg[r0 * 132 + m0]      = l00[r];
            lg[r0 * 132 + m0 + 16] = l01[r];
            lg[r1 * 132 + m0]      = l10[r];
            lg[r1 * 132 + m0 + 16] = l11[r];
        }
    }
    __syncthreads();

    // ================= phase 3: masked softmax (8 threads per token) =================
    {
        int t = tid >> 3, sub = tid & 7;
        int nv = nvis[b * SEQ + s0 + t];
        float pv[16];
        float mx = -3.0e38f;
        #pragma unroll
        for (int i = 0; i < 16; i++) {
            int m = sub * 16 + i;
            float vv = lg[t * 132 + m];
            pv[i] = vv;
            if (m < nv) mx = fmaxf(mx, vv);
        }
        mx = fmaxf(mx, __shfl_xor(mx, 1));
        mx = fmaxf(mx, __shfl_xor(mx, 2));
        mx = fmaxf(mx, __shfl_xor(mx, 4));
        float sum = 0.f;
        #pragma unroll
        for (int i = 0; i < 16; i++) {
            int m = sub * 16 + i;
            float e = (m < nv) ? __expf(pv[i] - mx) : 0.f;
            pv[i] = e;
            sum += e;
        }
        sum += __shfl_xor(sum, 1);
        sum += __shfl_xor(sum, 2);
        sum += __shfl_xor(sum, 4);
        float inv = (nv > 0) ? 1.0f / sum : 0.f;
        #pragma unroll
        for (int i = 0; i < 16; i++) {
            int m = sub * 16 + i;
            *(short*)(qPc + ((t * 256 + m * 2) ^ ((t & 7) << 4))) = f2b(pv[i] * inv);
        }
    }
    __syncthreads();

    // ================= phase 4: od = P @ V =================
    {
        f32x4 o00 = zero, o01 = zero, o10 = zero, o11 = zero;
        const short* vbp0 = vT_bf + ((size_t)b << 14) + (w * 32 + lr) * 128 + lq * 8;
        const short* vbp1 = vbp0 + 16 * 128;
        #pragma unroll
        for (int kk = 0; kk < 4; kk++) {
            short8v fa0 = *(short8v*)(qPc + ((lr * 256 + kk * 64 + lq * 16) ^ ((lr & 7) << 4)));
            short8v fa1 = *(short8v*)(qPc + (((16 + lr) * 256 + kk * 64 + lq * 16) ^ ((lr & 7) << 4)));
            short8v fb0 = *(const short8v*)(vbp0 + kk * 32);
            short8v fb1 = *(const short8v*)(vbp1 + kk * 32);
            o00 = MFMA(fa0, fb0, o00); o01 = MFMA(fa0, fb1, o01);
            o10 = MFMA(fa1, fb0, o10); o11 = MFMA(fa1, fb1, o11);
        }
        int d0 = w * 32 + lr;
        #pragma unroll
        for (int r = 0; r < 4; r++) {
            int r0 = lq * 4 + r, r1 = 16 + r0;
            *(short*)(odc + ((r0 * 256 + d0 * 2) ^ ((r0 & 7) << 4)))        = f2b(o00[r]);
            *(short*)(odc + ((r0 * 256 + (d0 + 16) * 2) ^ ((r0 & 7) << 4))) = f2b(o01[r]);
            *(short*)(odc + ((r1 * 256 + d0 * 2) ^ ((r1 & 7) << 4)))        = f2b(o10[r]);
            *(short*)(odc + ((r1 * 256 + (d0 + 16) * 2) ^ ((r1 & 7) << 4))) = f2b(o11[r]);
        }
    }
    __syncthreads();

    // ================= phase 5: out = od @ Wo + bo =================
    {
        short8v af0[4], af1[4];
        #pragma unroll
        for (int kk = 0; kk < 4; kk++) {
            af0[kk] = *(short8v*)(odc + ((lr * 256 + kk * 64 + lq * 16) ^ ((lr & 7) << 4)));
            af1[kk] = *(short8v*)(odc + (((16 + lr) * 256 + kk * 64 + lq * 16) ^ ((lr & 7) << 4)));
        }
        #pragma unroll
        for (int pass = 0; pass < 4; pass++) {
            int ep = w * 256 + pass * 64;
            f32x4 ac0[4], ac1[4];
            #pragma unroll
            for (int e2 = 0; e2 < 4; e2++) { ac0[e2] = zero; ac1[e2] = zero; }
            #pragma unroll
            for (int kk = 0; kk < 4; kk++) {
                #pragma unroll
                for (int e2 = 0; e2 < 4; e2++) {
                    const short8v bb = *(const short8v*)(WoT + (ep + e2 * 16 + lr) * 128 + kk * 32 + lq * 8);
                    ac0[e2] = MFMA(af0[kk], bb, ac0[e2]);
                    ac1[e2] = MFMA(af1[kk], bb, ac1[e2]);
                }
            }
            #pragma unroll
            for (int e2 = 0; e2 < 4; e2++) {
                int col = ep + e2 * 16 + lr;
                float bov = bo[col];
                #pragma unroll
                for (int r = 0; r < 4; r++) {
                    out[(hrow + lq * 4 + r) * EMB + col]      = ac0[e2][r] + bov;
                    out[(hrow + 16 + lq * 4 + r) * EMB + col] = ac1[e2][r] + bov;
                }
            }
        }
    }
}

extern "C" void kernel_launch(void* const* d_in, const int* in_sizes, int n_in,
                              void* d_out, int out_size, void* d_ws, size_t ws_size,
                              hipStream_t stream) {
    const int*   ids    = (const int*)d_in[0];
    const float* hidden = (const float*)d_in[1];
    const float* Wv     = (const float*)d_in[2];
    const float* bv     = (const float*)d_in[3];
    const float* Wq     = (const float*)d_in[4];
    const float* bq     = (const float*)d_in[5];
    const float* Wk     = (const float*)d_in[6];
    const float* bk     = (const float*)d_in[7];
    const float* Wvt    = (const float*)d_in[8];
    const float* bvt    = (const float*)d_in[9];
    const float* Wo     = (const float*)d_in[10];
    const float* bo     = (const float*)d_in[11];

    char* ws = (char*)d_ws;
    int*   pos   = (int*)ws;                                   // 4 KB
    int*   nvis  = (int*)(ws + (4 << 10));                     // 256 KB
    float* stat  = (float*)(ws + (260 << 10));                 // 512 KB
    short* k_bf  = (short*)(ws + (772 << 10));                 // 256 KB
    short* vT_bf = (short*)(ws + (1028 << 10));                // 256 KB
    short* WqT   = (short*)(ws + (1284 << 10));                // 256 KB
    short* WoT   = (short*)(ws + (1540 << 10));                // 256 KB (total 1796 KB)

    seg_kernel<<<NB, 1024, 0, stream>>>(ids, pos, nvis);
    prep_w<<<512, 256, 0, stream>>>(Wq, Wo, WqT, WoT);
    dim3 g2(MAX_SEN, NB);
    static_kernel<<<g2, 128, 0, stream>>>(hidden, Wv, bv, pos, stat);
    kv_kernel<<<g2, 128, 0, stream>>>(stat, Wk, bk, Wvt, bvt, k_bf, vT_bf);
    attn_kernel<<<NB * (SEQ / TS), 256, 0, stream>>>(hidden, WqT, bq, k_bf, vT_bf, WoT, bo,
                                                     nvis, (float*)d_out);
}

// Round 3
// 243.599 us; speedup vs baseline: 1.0484x; 1.0484x over previous
//
#include <hip/hip_runtime.h>
#include <hip/hip_bf16.h>

#define MASK_ID 3
#define MAX_SEN 128
#define NB 8
#define SEQ 8192
#define EMB 1024
#define DIM 128
#define TS 32

typedef __attribute__((ext_vector_type(8))) short short8v;   // 8 bf16 (4 VGPRs)
typedef __attribute__((ext_vector_type(4))) float f32x4;     // MFMA accumulator

#define MFMA(a, b, c) __builtin_amdgcn_mfma_f32_16x16x32_bf16(a, b, c, 0, 0, 0)

// fp32 -> bf16 (round-nearest-even), returned as raw short
__device__ __forceinline__ short f2b(float x) {
    union { float f; unsigned u; } v; v.f = x;
    unsigned r = (v.u + 0x7FFFu + ((v.u >> 16) & 1u)) >> 16;
    return (short)r;
}

// ---------------- Kernel 1: per-row scan -> mask positions + nvis ----------------
__global__ __launch_bounds__(1024) void seg_kernel(const int* __restrict__ ids,
                                                   int* __restrict__ pos,
                                                   int* __restrict__ nvis) {
    int b = blockIdx.x;
    int tid = threadIdx.x;
    __shared__ int sc[1024];
    __shared__ int sc2[1024];
    const int PER = SEQ / 1024;  // 8
    int base = b * SEQ + tid * PER;

    int ids_l[PER];
    int cnt = 0;
    #pragma unroll
    for (int j = 0; j < PER; j++) {
        ids_l[j] = ids[base + j];
        cnt += (ids_l[j] == MASK_ID) ? 1 : 0;
    }
    if (tid < MAX_SEN) pos[b * MAX_SEN + tid] = -1;
    sc[tid] = cnt;
    __syncthreads();

    int* src = sc;
    int* dst = sc2;
    for (int off = 1; off < 1024; off <<= 1) {
        int v = src[tid];
        if (tid >= off) v += src[tid - off];
        dst[tid] = v;
        __syncthreads();
        int* t = src; src = dst; dst = t;
    }
    int incl = src[tid];
    int run = incl - cnt;  // exclusive prefix

    #pragma unroll
    for (int j = 0; j < PER; j++) {
        if (ids_l[j] == MASK_ID) {
            run++;
            if (run <= MAX_SEN) pos[b * MAX_SEN + run - 1] = tid * PER + j;
        }
        int nv = run; if (nv > MAX_SEN) nv = MAX_SEN;
        nvis[base + j] = nv;
    }
}

// ---------------- Kernel 2: transpose+convert weights to bf16 ----------------
__global__ __launch_bounds__(256) void prep_w(const float* __restrict__ Wq,
                                              const float* __restrict__ Wo,
                                              short* __restrict__ WqT,
                                              short* __restrict__ WoT) {
    int idx = blockIdx.x * 256 + threadIdx.x;      // 0 .. 131071
    int d = idx >> 10, e = idx & 1023;
    WqT[idx] = f2b(Wq[e * DIM + d]);
    int e2 = idx >> 7, d2 = idx & 127;
    WoT[idx] = f2b(Wo[d2 * EMB + e2]);
}

// ---------------- Kernel 3: fused static+kv: k_bf[m][d], vT_bf[d][m] (bf16) ----------------
__global__ __launch_bounds__(128) void statkv_kernel(const float* __restrict__ hidden,
                                                     const float* __restrict__ Wv, const float* __restrict__ bv,
                                                     const float* __restrict__ Wk, const float* __restrict__ bk,
                                                     const float* __restrict__ Wvt, const float* __restrict__ bvt,
                                                     const int* __restrict__ pos,
                                                     short* __restrict__ k_bf, short* __restrict__ vT_bf) {
    int m = blockIdx.x, b = blockIdx.y;
    int d = threadIdx.x;
    __shared__ float h[EMB];
    __shared__ float srow[DIM];
    int p = pos[b * MAX_SEN + m];   // uniform across block
    float acc = bv[d];
    if (p >= 0) {
        const float* hp = hidden + ((size_t)b * SEQ + p) * EMB;
        for (int e = d; e < EMB; e += 128) h[e] = hp[e];
        __syncthreads();
        for (int e = 0; e < EMB; e++) acc += h[e] * Wv[e * DIM + d];
    }
    srow[d] = acc;
    __syncthreads();
    float ka = bk[d], va = bvt[d];
    for (int e = 0; e < DIM; e++) {
        float sv = srow[e];
        ka += sv * Wk[e * DIM + d];
        va += sv * Wvt[e * DIM + d];
    }
    k_bf[((size_t)b * MAX_SEN + m) * DIM + d] = f2b(ka);
    vT_bf[((size_t)b * DIM + d) * MAX_SEN + m] = f2b(va);
}

// ---------------- Kernel 4: fused MFMA attention per 32-token tile ----------------
__global__ __launch_bounds__(256, 4) void attn_kernel(
    const float* __restrict__ hidden,
    const short* __restrict__ WqT, const float* __restrict__ bq,
    const short* __restrict__ k_bf, const short* __restrict__ vT_bf,
    const short* __restrict__ WoT, const float* __restrict__ bo,
    const int* __restrict__ nvis,
    float* __restrict__ out) {
    int blk = blockIdx.x;
    int b  = blk >> 8;             // 256 tiles per batch
    int s0 = (blk & 255) * TS;
    int tid = threadIdx.x;
    int lane = tid & 63;
    int w  = tid >> 6;             // wave 0..3
    int lr = lane & 15;
    int lq = lane >> 4;            // quarter 0..3

    // hA (16384 B, phase 1) and lg (16896 B, phases 2-3) are never live together
    __shared__ char uAbuf[32 * 132 * 4];
    __shared__ short qP[32 * 128];    // q then P, bf16, swizzled rows of 256B
    __shared__ short odB[32 * 128];   // attn output (d-space), bf16, swizzled

    char* hAc = uAbuf;
    float* lg = (float*)uAbuf;
    char* qPc = (char*)qP;
    char* odc = (char*)odB;

    const size_t hrow = (size_t)b * SEQ + s0;
    f32x4 zero = {0.f, 0.f, 0.f, 0.f};

    // ================= phase 1: q = (H @ Wq + bq) * scale =================
    // T14 async-stage: prefetch chunk ec+1 into regs while MFMAing chunk ec.
    float4 pf[8];
    #pragma unroll
    for (int g = 0; g < 4; g++) {
        int G = tid + g * 256;
        int t = G >> 5, e8 = (G & 31) << 3;
        const float* hp = hidden + (hrow + t) * EMB + e8;
        pf[2 * g]     = *(const float4*)hp;
        pf[2 * g + 1] = *(const float4*)(hp + 4);
    }

    f32x4 a00 = zero, a01 = zero, a10 = zero, a11 = zero;
    for (int ec = 0; ec < 4; ec++) {
        __syncthreads();   // previous MFMA readers done with hA
        #pragma unroll
        for (int g = 0; g < 4; g++) {
            int G = tid + g * 256;
            int t = G >> 5, e8 = (G & 31) << 3;
            short8v hh;
            hh[0] = f2b(pf[2 * g].x); hh[1] = f2b(pf[2 * g].y);
            hh[2] = f2b(pf[2 * g].z); hh[3] = f2b(pf[2 * g].w);
            hh[4] = f2b(pf[2 * g + 1].x); hh[5] = f2b(pf[2 * g + 1].y);
            hh[6] = f2b(pf[2 * g + 1].z); hh[7] = f2b(pf[2 * g + 1].w);
            int byte = (t * 512 + e8 * 2) ^ ((t & 7) << 4);
            *(short8v*)(hAc + byte) = hh;
        }
        if (ec < 3) {
            #pragma unroll
            for (int g = 0; g < 4; g++) {
                int G = tid + g * 256;
                int t = G >> 5, e8 = (G & 31) << 3;
                const float* hp = hidden + (hrow + t) * EMB + (ec + 1) * 256 + e8;
                pf[2 * g]     = *(const float4*)hp;
                pf[2 * g + 1] = *(const float4*)(hp + 4);
            }
        }
        __syncthreads();
        const short* bp0 = WqT + (w * 32 + lr) * 1024 + ec * 256 + lq * 8;
        const short* bp1 = bp0 + 16 * 1024;
        #pragma unroll
        for (int kk = 0; kk < 8; kk++) {
            short8v fa0 = *(short8v*)(hAc + ((lr * 512 + kk * 64 + lq * 16) ^ ((lr & 7) << 4)));
            short8v fa1 = *(short8v*)(hAc + (((16 + lr) * 512 + kk * 64 + lq * 16) ^ ((lr & 7) << 4)));
            short8v fb0 = *(const short8v*)(bp0 + kk * 32);
            short8v fb1 = *(const short8v*)(bp1 + kk * 32);
            a00 = MFMA(fa0, fb0, a00); a01 = MFMA(fa0, fb1, a01);
            a10 = MFMA(fa1, fb0, a10); a11 = MFMA(fa1, fb1, a11);
        }
    }
    {
        const float scale = 0.08838834764831845f;  // 128^-0.5
        int d0 = w * 32 + lr;
        float bq0 = bq[d0], bq1 = bq[d0 + 16];
        #pragma unroll
        for (int r = 0; r < 4; r++) {
            int r0 = lq * 4 + r, r1 = 16 + r0;
            *(short*)(qPc + ((r0 * 256 + d0 * 2) ^ ((r0 & 7) << 4)))        = f2b((a00[r] + bq0) * scale);
            *(short*)(qPc + ((r0 * 256 + (d0 + 16) * 2) ^ ((r0 & 7) << 4))) = f2b((a01[r] + bq1) * scale);
            *(short*)(qPc + ((r1 * 256 + d0 * 2) ^ ((r1 & 7) << 4)))        = f2b((a10[r] + bq0) * scale);
            *(short*)(qPc + ((r1 * 256 + (d0 + 16) * 2) ^ ((r1 & 7) << 4))) = f2b((a11[r] + bq1) * scale);
        }
    }
    __syncthreads();

    // ================= phase 2: logits = q @ K^T  (lg aliases hA; safe: hA dead) =================
    {
        f32x4 l00 = zero, l01 = zero, l10 = zero, l11 = zero;
        const short* kbp0 = k_bf + ((size_t)b << 14) + (w * 32 + lr) * 128 + lq * 8;
        const short* kbp1 = kbp0 + 16 * 128;
        #pragma unroll
        for (int kk = 0; kk < 4; kk++) {
            short8v fa0 = *(short8v*)(qPc + ((lr * 256 + kk * 64 + lq * 16) ^ ((lr & 7) << 4)));
            short8v fa1 = *(short8v*)(qPc + (((16 + lr) * 256 + kk * 64 + lq * 16) ^ ((lr & 7) << 4)));
            short8v fb0 = *(const short8v*)(kbp0 + kk * 32);
            short8v fb1 = *(const short8v*)(kbp1 + kk * 32);
            l00 = MFMA(fa0, fb0, l00); l01 = MFMA(fa0, fb1, l01);
            l10 = MFMA(fa1, fb0, l10); l11 = MFMA(fa1, fb1, l11);
        }
        int m0 = w * 32 + lr;
        #pragma unroll
        for (int r = 0; r < 4; r++) {
            int r0 = lq * 4 + r, r1 = 16 + r0;
            lg[r0 * 132 + m0]      = l00[r];
            lg[r0 * 132 + m0 + 16] = l01[r];
            lg[r1 * 132 + m0]      = l10[r];
            lg[r1 * 132 + m0 + 16] = l11[r];
        }
    }
    __syncthreads();

    // ================= phase 3: masked softmax (8 threads per token) =================
    {
        int t = tid >> 3, sub = tid & 7;
        int nv = nvis[b * SEQ + s0 + t];
        float pv[16];
        float mx = -3.0e38f;
        #pragma unroll
        for (int i = 0; i < 16; i++) {
            int m = sub * 16 + i;
            float vv = lg[t * 132 + m];
            pv[i] = vv;
            if (m < nv) mx = fmaxf(mx, vv);
        }
        mx = fmaxf(mx, __shfl_xor(mx, 1));
        mx = fmaxf(mx, __shfl_xor(mx, 2));
        mx = fmaxf(mx, __shfl_xor(mx, 4));
        float sum = 0.f;
        #pragma unroll
        for (int i = 0; i < 16; i++) {
            int m = sub * 16 + i;
            float e = (m < nv) ? __expf(pv[i] - mx) : 0.f;
            pv[i] = e;
            sum += e;
        }
        sum += __shfl_xor(sum, 1);
        sum += __shfl_xor(sum, 2);
        sum += __shfl_xor(sum, 4);
        float inv = (nv > 0) ? 1.0f / sum : 0.f;
        #pragma unroll
        for (int i = 0; i < 16; i++) {
            int m = sub * 16 + i;
            *(short*)(qPc + ((t * 256 + m * 2) ^ ((t & 7) << 4))) = f2b(pv[i] * inv);
        }
    }
    __syncthreads();

    // ================= phase 4: od = P @ V =================
    {
        f32x4 o00 = zero, o01 = zero, o10 = zero, o11 = zero;
        const short* vbp0 = vT_bf + ((size_t)b << 14) + (w * 32 + lr) * 128 + lq * 8;
        const short* vbp1 = vbp0 + 16 * 128;
        #pragma unroll
        for (int kk = 0; kk < 4; kk++) {
            short8v fa0 = *(short8v*)(qPc + ((lr * 256 + kk * 64 + lq * 16) ^ ((lr & 7) << 4)));
            short8v fa1 = *(short8v*)(qPc + (((16 + lr) * 256 + kk * 64 + lq * 16) ^ ((lr & 7) << 4)));
            short8v fb0 = *(const short8v*)(vbp0 + kk * 32);
            short8v fb1 = *(const short8v*)(vbp1 + kk * 32);
            o00 = MFMA(fa0, fb0, o00); o01 = MFMA(fa0, fb1, o01);
            o10 = MFMA(fa1, fb0, o10); o11 = MFMA(fa1, fb1, o11);
        }
        int d0 = w * 32 + lr;
        #pragma unroll
        for (int r = 0; r < 4; r++) {
            int r0 = lq * 4 + r, r1 = 16 + r0;
            *(short*)(odc + ((r0 * 256 + d0 * 2) ^ ((r0 & 7) << 4)))        = f2b(o00[r]);
            *(short*)(odc + ((r0 * 256 + (d0 + 16) * 2) ^ ((r0 & 7) << 4))) = f2b(o01[r]);
            *(short*)(odc + ((r1 * 256 + d0 * 2) ^ ((r1 & 7) << 4)))        = f2b(o10[r]);
            *(short*)(odc + ((r1 * 256 + (d0 + 16) * 2) ^ ((r1 & 7) << 4))) = f2b(o11[r]);
        }
    }
    __syncthreads();

    // ================= phase 5: out = od @ Wo + bo =================
    {
        short8v af0[4], af1[4];
        #pragma unroll
        for (int kk = 0; kk < 4; kk++) {
            af0[kk] = *(short8v*)(odc + ((lr * 256 + kk * 64 + lq * 16) ^ ((lr & 7) << 4)));
            af1[kk] = *(short8v*)(odc + (((16 + lr) * 256 + kk * 64 + lq * 16) ^ ((lr & 7) << 4)));
        }
        #pragma unroll
        for (int pass = 0; pass < 4; pass++) {
            int ep = w * 256 + pass * 64;
            f32x4 ac0[4], ac1[4];
            #pragma unroll
            for (int e2 = 0; e2 < 4; e2++) { ac0[e2] = zero; ac1[e2] = zero; }
            #pragma unroll
            for (int kk = 0; kk < 4; kk++) {
                #pragma unroll
                for (int e2 = 0; e2 < 4; e2++) {
                    const short8v bb = *(const short8v*)(WoT + (ep + e2 * 16 + lr) * 128 + kk * 32 + lq * 8);
                    ac0[e2] = MFMA(af0[kk], bb, ac0[e2]);
                    ac1[e2] = MFMA(af1[kk], bb, ac1[e2]);
                }
            }
            #pragma unroll
            for (int e2 = 0; e2 < 4; e2++) {
                int col = ep + e2 * 16 + lr;
                float bov = bo[col];
                #pragma unroll
                for (int r = 0; r < 4; r++) {
                    out[(hrow + lq * 4 + r) * EMB + col]      = ac0[e2][r] + bov;
                    out[(hrow + 16 + lq * 4 + r) * EMB + col] = ac1[e2][r] + bov;
                }
            }
        }
    }
}

extern "C" void kernel_launch(void* const* d_in, const int* in_sizes, int n_in,
                              void* d_out, int out_size, void* d_ws, size_t ws_size,
                              hipStream_t stream) {
    const int*   ids    = (const int*)d_in[0];
    const float* hidden = (const float*)d_in[1];
    const float* Wv     = (const float*)d_in[2];
    const float* bv     = (const float*)d_in[3];
    const float* Wq     = (const float*)d_in[4];
    const float* bq     = (const float*)d_in[5];
    const float* Wk     = (const float*)d_in[6];
    const float* bk     = (const float*)d_in[7];
    const float* Wvt    = (const float*)d_in[8];
    const float* bvt    = (const float*)d_in[9];
    const float* Wo     = (const float*)d_in[10];
    const float* bo     = (const float*)d_in[11];

    char* ws = (char*)d_ws;
    int*   pos   = (int*)ws;                                   // 4 KB
    int*   nvis  = (int*)(ws + (4 << 10));                     // 256 KB
    short* k_bf  = (short*)(ws + (260 << 10));                 // 256 KB
    short* vT_bf = (short*)(ws + (516 << 10));                 // 256 KB
    short* WqT   = (short*)(ws + (772 << 10));                 // 256 KB
    short* WoT   = (short*)(ws + (1028 << 10));                // 256 KB (total 1284 KB)

    seg_kernel<<<NB, 1024, 0, stream>>>(ids, pos, nvis);
    prep_w<<<512, 256, 0, stream>>>(Wq, Wo, WqT, WoT);
    dim3 g2(MAX_SEN, NB);
    statkv_kernel<<<g2, 128, 0, stream>>>(hidden, Wv, bv, Wk, bk, Wvt, bvt, pos, k_bf, vT_bf);
    attn_kernel<<<NB * (SEQ / TS), 256, 0, stream>>>(hidden, WqT, bq, k_bf, vT_bf, WoT, bo,
                                                     nvis, (float*)d_out);
}